// Round 12
// baseline (372.060 us; speedup 1.0000x reference)
//
#include <hip/hip_runtime.h>

// ---------------------------------------------------------------------------
// 2-layer GCN forward, pull-mode, bf16 tables, MFMA GEMM1, FUSED gemm2.
//
// R17: fuse gemm2 INTO gather1.  R16 measurement: gather2=54us FETCH 157MB
// (same pattern-roofline regime as gather1's 81); gemms each <54; +4
// dispatches cost +21us -> boundary ~4-5us each (12 dispatches ~ 50us).
// gemm2 is per-row (h2[v]=dinv[v]*(h1[v]@W2)) and gather1's wave holds one
// node's full h1 row -> in-wave 128x64 matvec (W2 bf16 in 17KB LDS, row
// broadcast via LDS, lane j owns output j, conflict-free b128 reads) writes
// h2 directly.  Eliminates h1 table (51MB traffic), gemm2 dispatch+boundary,
// gemm2 work; matvec VALU hides in gather1's ~60% idle VALU slots.
// gather1 stays split 4x + gather2 split 2x -> top-5 cutoff ~27us so gemm1
// surfaces next round if it is the remaining sink.
//
// ws (4B units): dinv[Np] rowptr[Np+4] counts[MAXBK*NB] bsum[128]
//   csr_src[E] tmpP[E] | h ushort[N*128] | h2 ushort[N*64]
// ---------------------------------------------------------------------------

typedef unsigned int uint;
typedef unsigned short ushort;
typedef __attribute__((ext_vector_type(8))) short bf16x8;
typedef __attribute__((ext_vector_type(8))) ushort u16x8;
typedef __attribute__((ext_vector_type(4))) float f32x4;

#define BSHIFT 8          // nodes per bucket = 256
#define MAXBK  512        // max buckets (N <= 131072)
#define NB     256        // hist/scatter blocks
#define CAP    8192       // LDS-staged edges per bucket (avg ~4096)

__device__ inline ushort f2bf(float f) {
    uint u = __float_as_uint(f);
    return (ushort)((u + 0x7fffu + ((u >> 16) & 1u)) >> 16);  // RNE
}
__device__ inline float bf_lo(uint u) { return __uint_as_float(u << 16); }
__device__ inline float bf_hi(uint u) { return __uint_as_float(u & 0xffff0000u); }
__device__ inline float bf2f(ushort u) { return __uint_as_float((uint)u << 16); }

// ---- pass 1: per-block bucket histogram (LDS atomics only) ----
__global__ __launch_bounds__(256) void hist_kernel(const int* __restrict__ tgt,
                                                   int* __restrict__ counts,
                                                   int E, int chunk, int nbk) {
    __shared__ int hist[MAXBK];
    int t = threadIdx.x, b = blockIdx.x;
    for (int i = t; i < nbk; i += 256) hist[i] = 0;
    __syncthreads();
    int s = b * chunk, e = min(E, s + chunk);
    int i = s + t * 4;
    for (; i + 3 < e; i += 1024) {
        int4 tv = *(const int4*)&tgt[i];
        atomicAdd(&hist[tv.x >> BSHIFT], 1);
        atomicAdd(&hist[tv.y >> BSHIFT], 1);
        atomicAdd(&hist[tv.z >> BSHIFT], 1);
        atomicAdd(&hist[tv.w >> BSHIFT], 1);
    }
    if (i < e)
        for (int k = i; k < e; ++k) atomicAdd(&hist[tgt[k] >> BSHIFT], 1);
    __syncthreads();
    for (int i2 = t; i2 < nbk; i2 += 256) counts[i2 * NB + b] = hist[i2];
}

// ---- scan step 1: per-1024 partial sums of counts ----
__global__ __launch_bounds__(256) void scan_partial(const int* __restrict__ in,
                                                    int* __restrict__ bsum, int M) {
    int t = threadIdx.x, b = blockIdx.x;
    int base = b * 1024 + t * 4;
    int s = 0;
#pragma unroll
    for (int k = 0; k < 4; ++k) s += (base + k < M) ? in[base + k] : 0;
#pragma unroll
    for (int off = 32; off > 0; off >>= 1) s += __shfl_down(s, off, 64);
    __shared__ int ws[4];
    if ((t & 63) == 0) ws[t >> 6] = s;
    __syncthreads();
    if (t == 0) bsum[b] = ws[0] + ws[1] + ws[2] + ws[3];
}

// ---- scan step 2: exclusive scan of counts in place (bsum prefix fused) ----
__global__ __launch_bounds__(256) void scan_final_counts(int* __restrict__ counts,
                                                         const int* __restrict__ bsum,
                                                         int M) {
    int t = threadIdx.x, b = blockIdx.x;
    int lane = t & 63, wid = t >> 6;
    int p = 0;
    for (int i = t; i < b; i += 256) p += bsum[i];
#pragma unroll
    for (int off = 32; off > 0; off >>= 1) p += __shfl_down(p, off, 64);
    __shared__ int ps[4];
    if (lane == 0) ps[wid] = p;
    __syncthreads();
    int pre = ps[0] + ps[1] + ps[2] + ps[3];

    int base = b * 1024 + t * 4;
    int d[4];
#pragma unroll
    for (int k = 0; k < 4; ++k) d[k] = (base + k < M) ? counts[base + k] : 0;
    int tot = d[0] + d[1] + d[2] + d[3];
    int incl = tot;
#pragma unroll
    for (int off = 1; off < 64; off <<= 1) {
        int u = __shfl_up(incl, off, 64);
        if (lane >= off) incl += u;
    }
    __shared__ int wsum[4];
    if (lane == 63) wsum[wid] = incl;
    __syncthreads();
    int woff = 0;
    for (int w = 0; w < wid; ++w) woff += wsum[w];
    int run = incl - tot + woff + pre;
#pragma unroll
    for (int k = 0; k < 4; ++k) {
        if (base + k < M) counts[base + k] = run;
        run += d[k];
    }
}

// ---- pass 2: scatter edges into bucket-contiguous packed tmp ----
__global__ __launch_bounds__(256) void bucket_scatter(const int* __restrict__ src,
                                                      const int* __restrict__ tgt,
                                                      const int* __restrict__ offsets,
                                                      int* __restrict__ tmpP,
                                                      int E, int chunk, int nbk) {
    __shared__ int cur[MAXBK];
    int t = threadIdx.x, b = blockIdx.x;
    for (int i = t; i < nbk; i += 256) cur[i] = offsets[i * NB + b];
    __syncthreads();
    int s = b * chunk, e = min(E, s + chunk);
    int i = s + t * 4;
    for (; i + 3 < e; i += 1024) {
        int4 sv = *(const int4*)&src[i];
        int4 tv = *(const int4*)&tgt[i];
        int p0 = atomicAdd(&cur[tv.x >> BSHIFT], 1);
        tmpP[p0] = (sv.x << BSHIFT) | (tv.x & 255);
        int p1 = atomicAdd(&cur[tv.y >> BSHIFT], 1);
        tmpP[p1] = (sv.y << BSHIFT) | (tv.y & 255);
        int p2 = atomicAdd(&cur[tv.z >> BSHIFT], 1);
        tmpP[p2] = (sv.z << BSHIFT) | (tv.z & 255);
        int p3 = atomicAdd(&cur[tv.w >> BSHIFT], 1);
        tmpP[p3] = (sv.w << BSHIFT) | (tv.w & 255);
    }
    if (i < e) {
        for (int k = i; k < e; ++k) {
            int tg = tgt[k];
            int p = atomicAdd(&cur[tg >> BSHIFT], 1);
            tmpP[p] = (src[k] << BSHIFT) | (tg & 255);
        }
    }
}

// ---- pass 3 (fused): per-bucket deg count + scan + rowptr/dinv + csr fill ----
__global__ __launch_bounds__(256) void bucket_finish(const int* __restrict__ tmpP,
                                                     const int* __restrict__ offsets,
                                                     int* __restrict__ rowptr,
                                                     float* __restrict__ dinv,
                                                     int* __restrict__ csr_src,
                                                     int N, int E, int nbk) {
    __shared__ int stage[CAP];
    __shared__ int cnt[256];
    __shared__ int wsum[4];
    int t = threadIdx.x, b = blockIdx.x;
    cnt[t] = 0;
    __syncthreads();
    int s = offsets[b * NB];
    int e = (b + 1 < nbk) ? offsets[(b + 1) * NB] : E;
    int m = e - s;
    for (int i = t; i < m; i += 256) {
        int ed = tmpP[s + i];
        if (i < CAP) stage[i] = ed;
        atomicAdd(&cnt[ed & 255], 1);
    }
    __syncthreads();
    int lane = t & 63, wid = t >> 6;
    int d = cnt[t];
    int incl = d;
#pragma unroll
    for (int off = 1; off < 64; off <<= 1) {
        int u = __shfl_up(incl, off, 64);
        if (lane >= off) incl += u;
    }
    if (lane == 63) wsum[wid] = incl;
    __syncthreads();
    int woff = 0;
    for (int w = 0; w < wid; ++w) woff += wsum[w];
    int excl = s + incl - d + woff;
    int node = b * 256 + t;
    if (node < N) {
        rowptr[node] = excl;
        dinv[node] = rsqrtf((float)d + 1.0f);  // +1 self-loop
    }
    if (b == nbk - 1 && t == 255) rowptr[N] = E;
    cnt[t] = excl;  // reuse as cursor
    __syncthreads();
    for (int i = t; i < m; i += 256) {
        int ed = (i < CAP) ? stage[i] : tmpP[s + i];
        int p = atomicAdd(&cnt[ed & 255], 1);
        csr_src[p] = ed >> BSHIFT;
    }
}

// ---- MFMA GEMM1: h[N,128](bf16) = dinv[row] * (x[N,128] @ W1[128,128]) ----
__global__ __launch_bounds__(256) void gemm1_k(const float* __restrict__ A,
                                               const float* __restrict__ W,
                                               const float* __restrict__ dinv,
                                               ushort* __restrict__ C, int N) {
    constexpr int M = 128;
    constexpr int WTS = 136;           // padded row stride (bf16)
    __shared__ ushort WT[M * WTS];     // WT[n][k] = W[k][n]
    const int tid = threadIdx.x;
    for (int i = tid; i < 128 * (M / 4); i += 256) {
        int k = i / (M / 4);
        int n0 = (i % (M / 4)) * 4;
        float4 w = *(const float4*)&W[k * M + n0];
        WT[(n0 + 0) * WTS + k] = f2bf(w.x);
        WT[(n0 + 1) * WTS + k] = f2bf(w.y);
        WT[(n0 + 2) * WTS + k] = f2bf(w.z);
        WT[(n0 + 3) * WTS + k] = f2bf(w.w);
    }
    __syncthreads();

    const int wv = tid >> 6, lane = tid & 63;
    const int quad = lane >> 4, mrow = lane & 15;
    const int r0 = blockIdx.x * 128 + wv * 16 + mrow;   // half 0 row
    const int r1 = r0 + 64;                              // half 1 row
    const int a0i = min(r0, N - 1);    // clamp loads; stores guarded
    const int a1i = min(r1, N - 1);

    f32x4 acc0[M / 16], acc1[M / 16];
#pragma unroll
    for (int t = 0; t < M / 16; ++t) {
        acc0[t] = (f32x4){0.f, 0.f, 0.f, 0.f};
        acc1[t] = (f32x4){0.f, 0.f, 0.f, 0.f};
    }

#pragma unroll
    for (int ks = 0; ks < 4; ++ks) {
        const int k0 = ks * 32 + quad * 8;
        bf16x8 af0, af1;
        const float* ar0 = A + (size_t)a0i * 128;
        const float* ar1 = A + (size_t)a1i * 128;
        float4 x0 = *(const float4*)&ar0[k0];
        float4 y0 = *(const float4*)&ar0[k0 + 4];
        float4 x1 = *(const float4*)&ar1[k0];
        float4 y1 = *(const float4*)&ar1[k0 + 4];
        af0[0] = (short)f2bf(x0.x); af0[1] = (short)f2bf(x0.y);
        af0[2] = (short)f2bf(x0.z); af0[3] = (short)f2bf(x0.w);
        af0[4] = (short)f2bf(y0.x); af0[5] = (short)f2bf(y0.y);
        af0[6] = (short)f2bf(y0.z); af0[7] = (short)f2bf(y0.w);
        af1[0] = (short)f2bf(x1.x); af1[1] = (short)f2bf(x1.y);
        af1[2] = (short)f2bf(x1.z); af1[3] = (short)f2bf(x1.w);
        af1[4] = (short)f2bf(y1.x); af1[5] = (short)f2bf(y1.y);
        af1[6] = (short)f2bf(y1.z); af1[7] = (short)f2bf(y1.w);
#pragma unroll
        for (int t = 0; t < M / 16; ++t) {
            bf16x8 bfr = *(const bf16x8*)&WT[(t * 16 + mrow) * WTS + k0];
            acc0[t] = __builtin_amdgcn_mfma_f32_16x16x32_bf16(af0, bfr, acc0[t], 0, 0, 0);
            acc1[t] = __builtin_amdgcn_mfma_f32_16x16x32_bf16(af1, bfr, acc1[t], 0, 0, 0);
        }
    }

    const int ob0 = blockIdx.x * 128 + wv * 16 + quad * 4;
#pragma unroll
    for (int r = 0; r < 4; ++r) {
        int o0 = ob0 + r;
        if (o0 < N) {
            float dv = dinv[o0];   // pre-scale row into the gather table
#pragma unroll
            for (int t = 0; t < M / 16; ++t)
                C[(size_t)o0 * M + t * 16 + mrow] = f2bf(dv * acc0[t][r]);
        }
        int o1 = ob0 + 64 + r;
        if (o1 < N) {
            float dv = dinv[o1];
#pragma unroll
            for (int t = 0; t < M / 16; ++t)
                C[(size_t)o1 * M + t * 16 + mrow] = f2bf(dv * acc1[t][r]);
        }
    }
}

// ---- FUSED gather1+gemm2: per node v (one wave each):
//   h1row = relu(dinv[v]*(sum_e h'[src] + h'[v]) + b1)   [bf16-rounded]
//   h2[v][j] = f2bf( dinv[v] * sum_k h1row[k]*W2bf[k][j] )   j = lane
// W2 bf16 in LDS as W2L[c][j][e] (c=k>>3, e=k&7): lane j reads b128 at
// &W2L[c*512 + j*8] (consecutive 16B -> conflict-free); row chunks broadcast
// from rowL (same addr all lanes -> free).
__global__ __launch_bounds__(256) void gather1f_k(
    const ushort* __restrict__ h, const int* __restrict__ rowptr,
    const int* __restrict__ csr_src, const float* __restrict__ dinv,
    const float* __restrict__ bias, const float* __restrict__ W2,
    ushort* __restrict__ h2, int nodeBeg, int nodeLim) {
    constexpr int D = 128;
    constexpr int Q = 16, G = 4;
    __shared__ ushort W2L[16 * 64 * 8];   // 16KB
    __shared__ ushort rowL[4 * 128];      // 1KB (per-wave h1 row)
    const int tid = threadIdx.x;
    // stage W2 -> bf16 LDS (coalesced fp32 reads)
    for (int i = tid; i < 8192; i += 256) {
        int k = i >> 6, j = i & 63;
        W2L[(k >> 3) * 512 + j * 8 + (k & 7)] = f2bf(W2[k * 64 + j]);
    }
    __syncthreads();   // before any wave's matvec (and before early return)

    const int wid = tid >> 6, lane = tid & 63;
    const int node = nodeBeg + blockIdx.x * 4 + wid;
    if (node >= nodeLim) return;          // wave-uniform exit
    const int g = lane >> 4, q = lane & 15;
    const int qoff = q * 8;
    const int beg = rowptr[node], end = rowptr[node + 1];
    float acc[8] = {};

    auto acc8 = [&](uint4 v) {
        acc[0] += bf_lo(v.x); acc[1] += bf_hi(v.x);
        acc[2] += bf_lo(v.y); acc[3] += bf_hi(v.y);
        acc[4] += bf_lo(v.z); acc[5] += bf_hi(v.z);
        acc[6] += bf_lo(v.w); acc[7] += bf_hi(v.w);
    };
    auto acc8m = [&](uint4 v, float m) {
        acc[0] += m * bf_lo(v.x); acc[1] += m * bf_hi(v.x);
        acc[2] += m * bf_lo(v.y); acc[3] += m * bf_hi(v.y);
        acc[4] += m * bf_lo(v.z); acc[5] += m * bf_hi(v.z);
        acc[6] += m * bf_lo(v.w); acc[7] += m * bf_hi(v.w);
    };

    int j = beg;
    for (; j + 4 * G <= end; j += 4 * G) {
        int s0 = csr_src[j + g];
        int s1 = csr_src[j + G + g];
        int s2 = csr_src[j + 2 * G + g];
        int s3 = csr_src[j + 3 * G + g];
        uint4 v0 = *(const uint4*)&h[(size_t)s0 * D + qoff];
        uint4 v1 = *(const uint4*)&h[(size_t)s1 * D + qoff];
        uint4 v2 = *(const uint4*)&h[(size_t)s2 * D + qoff];
        uint4 v3 = *(const uint4*)&h[(size_t)s3 * D + qoff];
        acc8(v0); acc8(v1); acc8(v2); acc8(v3);
    }
    for (; j < end; j += 2 * G) {
        int e0 = j + g, e1 = j + G + g;
        bool b0 = e0 < end, b1 = e1 < end;
        int s0 = b0 ? csr_src[e0] : 0;
        int s1 = b1 ? csr_src[e1] : 0;
        float m0 = b0 ? 1.0f : 0.0f;
        float m1 = b1 ? 1.0f : 0.0f;
        uint4 va = *(const uint4*)&h[(size_t)s0 * D + qoff];
        uint4 vb = *(const uint4*)&h[(size_t)s1 * D + qoff];
        acc8m(va, m0); acc8m(vb, m1);
    }
#pragma unroll
    for (int m2 = Q; m2 < 64; m2 <<= 1)
#pragma unroll
        for (int k = 0; k < 8; ++k) acc[k] += __shfl_xor(acc[k], m2, 64);

    {   // self-loop
        uint4 hv = *(const uint4*)&h[(size_t)node * D + qoff];
        acc8(hv);
    }
    const float di = dinv[node];
    if (g == 0) {   // lanes 0..15 hold the node's 128 features (8 each)
        float4 b0 = *(const float4*)&bias[qoff];
        float4 b1 = *(const float4*)&bias[qoff + 4];
        float r[8] = {di * acc[0] + b0.x, di * acc[1] + b0.y,
                      di * acc[2] + b0.z, di * acc[3] + b0.w,
                      di * acc[4] + b1.x, di * acc[5] + b1.y,
                      di * acc[6] + b1.z, di * acc[7] + b1.w};
        u16x8 o;
#pragma unroll
        for (int k = 0; k < 8; ++k) o[k] = f2bf(fmaxf(r[k], 0.0f));
        *(u16x8*)&rowL[wid * 128 + qoff] = o;   // h1 row, bf16-rounded
    }
    // in-wave 128x64 matvec: lane j computes h2[node][j]
    float acc2 = 0.0f;
#pragma unroll
    for (int c = 0; c < 16; ++c) {
        u16x8 rv = *(const u16x8*)&rowL[wid * 128 + c * 8];      // broadcast
        u16x8 wv = *(const u16x8*)&W2L[c * 512 + lane * 8];      // conflict-free
#pragma unroll
        for (int e = 0; e < 8; ++e) acc2 += bf2f(rv[e]) * bf2f(wv[e]);
    }
    h2[(size_t)node * 64 + lane] = f2bf(di * acc2);   // coalesced 128B/wave
}

// ---- gather2 over h2 table (D=64), fp32 row-major out ----
__global__ __launch_bounds__(256) void gather2_k(
    const ushort* __restrict__ h, const int* __restrict__ rowptr,
    const int* __restrict__ csr_src, const float* __restrict__ dinv,
    const float* __restrict__ bias, float* __restrict__ out,
    int nodeBeg, int nodeLim) {
    constexpr int D = 64;
    constexpr int Q = 8, G = 8;
    const int wid = threadIdx.x >> 6, lane = threadIdx.x & 63;
    const int node = nodeBeg + blockIdx.x * 4 + wid;
    if (node >= nodeLim) return;
    const int g = lane / Q, q = lane % Q;
    const int qoff = q * 8;
    const int beg = rowptr[node], end = rowptr[node + 1];
    float acc[8] = {};

    auto acc8 = [&](uint4 v) {
        acc[0] += bf_lo(v.x); acc[1] += bf_hi(v.x);
        acc[2] += bf_lo(v.y); acc[3] += bf_hi(v.y);
        acc[4] += bf_lo(v.z); acc[5] += bf_hi(v.z);
        acc[6] += bf_lo(v.w); acc[7] += bf_hi(v.w);
    };
    auto acc8m = [&](uint4 v, float m) {
        acc[0] += m * bf_lo(v.x); acc[1] += m * bf_hi(v.x);
        acc[2] += m * bf_lo(v.y); acc[3] += m * bf_hi(v.y);
        acc[4] += m * bf_lo(v.z); acc[5] += m * bf_hi(v.z);
        acc[6] += m * bf_lo(v.w); acc[7] += m * bf_hi(v.w);
    };

    int j = beg;
    for (; j + 4 * G <= end; j += 4 * G) {
        int s0 = csr_src[j + g];
        int s1 = csr_src[j + G + g];
        int s2 = csr_src[j + 2 * G + g];
        int s3 = csr_src[j + 3 * G + g];
        uint4 v0 = *(const uint4*)&h[(size_t)s0 * D + qoff];
        uint4 v1 = *(const uint4*)&h[(size_t)s1 * D + qoff];
        uint4 v2 = *(const uint4*)&h[(size_t)s2 * D + qoff];
        uint4 v3 = *(const uint4*)&h[(size_t)s3 * D + qoff];
        acc8(v0); acc8(v1); acc8(v2); acc8(v3);
    }
    for (; j < end; j += 2 * G) {
        int e0 = j + g, e1 = j + G + g;
        bool b0 = e0 < end, b1 = e1 < end;
        int s0 = b0 ? csr_src[e0] : 0;
        int s1 = b1 ? csr_src[e1] : 0;
        float m0 = b0 ? 1.0f : 0.0f;
        float m1 = b1 ? 1.0f : 0.0f;
        uint4 va = *(const uint4*)&h[(size_t)s0 * D + qoff];
        uint4 vb = *(const uint4*)&h[(size_t)s1 * D + qoff];
        acc8m(va, m0); acc8m(vb, m1);
    }
#pragma unroll
    for (int m2 = Q; m2 < 64; m2 <<= 1)
#pragma unroll
        for (int k = 0; k < 8; ++k) acc[k] += __shfl_xor(acc[k], m2, 64);

    {   // self-loop
        uint4 hv = *(const uint4*)&h[(size_t)node * D + qoff];
        acc8(hv);
    }
    if (g == 0) {
        const float di = dinv[node];
        float4 b0 = *(const float4*)&bias[qoff];
        float4 b1 = *(const float4*)&bias[qoff + 4];
        *(float4*)&out[(size_t)node * D + qoff] =
            make_float4(di * acc[0] + b0.x, di * acc[1] + b0.y,
                        di * acc[2] + b0.z, di * acc[3] + b0.w);
        *(float4*)&out[(size_t)node * D + qoff + 4] =
            make_float4(di * acc[4] + b1.x, di * acc[5] + b1.y,
                        di * acc[6] + b1.z, di * acc[7] + b1.w);
    }
}

extern "C" void kernel_launch(void* const* d_in, const int* in_sizes, int n_in,
                              void* d_out, int out_size, void* d_ws, size_t ws_size,
                              hipStream_t stream) {
    const float* x  = (const float*)d_in[0];
    const int*   ei = (const int*)d_in[1];
    const float* W1 = (const float*)d_in[2];
    const float* b1 = (const float*)d_in[3];
    const float* W2 = (const float*)d_in[4];
    const float* b2 = (const float*)d_in[5];
    float* out = (float*)d_out;

    const int N = in_sizes[0] / 128;
    const int E = in_sizes[1] / 2;
    const int* src = ei;
    const int* tgt = ei + E;

    const int nbk   = (N + 255) >> BSHIFT;               // buckets
    const int chunk = (((E + NB - 1) / NB) + 3) & ~3;    // ×4 for int4 alignment
    const int Mc    = nbk * NB;                          // counts length

    float* ws = (float*)d_ws;
    const size_t Np = (size_t)((N + 3) & ~3);
    float*  dinv    = ws;                            // Np
    int*    rowptr  = (int*)(ws + Np);               // Np+4
    int*    counts  = rowptr + Np + 4;               // MAXBK*NB (scanned in place)
    int*    bsum    = counts + MAXBK * NB;           // 128
    int*    csr_src = bsum + 128;                    // E
    int*    tmpP    = csr_src + E;                   // E packed (src<<8)|(tgt&255)
    ushort* h       = (ushort*)(tmpP + E);           // N*128 bf16 (gemm1 out)
    ushort* h2      = h + (size_t)N * 128;           // N*64 bf16 (fused out)

    const int nbc = (Mc + 1023) / 1024;

    // CSR build — 5 split kernels (verified ~4-16us total incl boundaries)
    hist_kernel<<<NB, 256, 0, stream>>>(tgt, counts, E, chunk, nbk);
    scan_partial<<<nbc, 256, 0, stream>>>(counts, bsum, Mc);
    scan_final_counts<<<nbc, 256, 0, stream>>>(counts, bsum, Mc);
    bucket_scatter<<<NB, 256, 0, stream>>>(src, tgt, counts, tmpP, E, chunk, nbk);
    bucket_finish<<<nbk, 256, 0, stream>>>(tmpP, counts, rowptr, dinv, csr_src, N, E, nbk);

    // Layer 1 GEMM: h = dinv * (x@W1)
    gemm1_k<<<(N + 127) / 128, 256, 0, stream>>>(x, W1, dinv, h, N);

    // Fused gather1+relu+gemm2 -> h2 (4 node-range quarters, measurement)
    {
        const int Nq = (N + 3) / 4;
        for (int qd = 0; qd < 4; ++qd) {
            int nb = qd * Nq, nl = min(N, nb + Nq);
            if (nb >= nl) break;
            gather1f_k<<<((nl - nb) + 3) / 4, 256, 0, stream>>>(
                h, rowptr, csr_src, dinv, b1, W2, h2, nb, nl);
        }
    }

    // gather2 -> out fp32 (2 halves)
    {
        const int Nh = (N + 1) / 2;
        for (int hd = 0; hd < 2; ++hd) {
            int nb = hd * Nh, nl = min(N, nb + Nh);
            if (nb >= nl) break;
            gather2_k<<<((nl - nb) + 3) / 4, 256, 0, stream>>>(
                h2, rowptr, csr_src, dinv, b2, out, nb, nl);
        }
    }
}